// Round 22
// baseline (73.821 us; speedup 1.0000x reference)
//
#include <hip/hip_runtime.h>
#include <hip/hip_bf16.h>

// Head attention: x[4,4096,1024] f32, Wq/Wk/Wv[1024,64] f32 -> out[4,4096,64] f32
// v22 = v21 with the LDS sizing bug fixed: projG's staged tile is 32 KB
//   (16384 shorts) but was declared as two 8192-short arrays with writes
//   running past the first -- UB (absmax 6.2e-2). Now one xs[16384].
//   xc:    x f32 -> xF bf16 frag-order (R5-verified layout)
//   projG: global_load_lds staged tile -> WtF-dbuf MFMA -> v17 epilogue
//   wtf/attnW byte-identical to v17.

#define BB 4
#define TT 4096
#define CC 1024
#define HH 64

typedef __attribute__((ext_vector_type(8))) short bf16x8;
typedef __attribute__((ext_vector_type(4))) float f32x4;

#if __has_builtin(__builtin_amdgcn_exp2f)
#define EXP2(x) __builtin_amdgcn_exp2f(x)
#else
#define EXP2(x) exp2f(x)
#endif

__device__ __forceinline__ short f2bf(float f) {
  union { float f; unsigned u; } v; v.f = f;
  unsigned r = v.u + 0x7fffu + ((v.u >> 16) & 1u);  // RNE
  return (short)(r >> 16);
}

__device__ __forceinline__ unsigned pk2bf(float lo, float hi) {  // packed RNE cvt
  __hip_bfloat162 p = __float22bfloat162_rn(make_float2(lo, hi));
  return *reinterpret_cast<unsigned*>(&p);
}

__device__ __forceinline__ void gload16(const short* g, short* l) {
  __builtin_amdgcn_global_load_lds(
      (const __attribute__((address_space(1))) void*)g,
      (__attribute__((address_space(3))) void*)l, 16, 0, 0);
}

#define WAITVM0() asm volatile("s_waitcnt vmcnt(0)" ::: "memory")

// ---------------- wtf: W -> WtF[nf 12][ks 32][lane 64][8] bf16 ---------------
// q part scaled by C^-0.5 * log2(e)  (softmax exp == exp2 of logits)
__global__ void wtf_kernel(const float* __restrict__ Wq, const float* __restrict__ Wk,
                           const float* __restrict__ Wv, short* __restrict__ WtF) {
  int idx = blockIdx.x * 256 + threadIdx.x;       // 24576
  int lane = idx & 63, ks = (idx >> 6) & 31, nf = idx >> 11;
  int l15 = lane & 15, lg = lane >> 4;
  int n = nf * 16 + l15;
  const float* W = (n < HH) ? Wq : ((n < 2 * HH) ? Wk : Wv);
  float sc = (n < HH) ? (0.03125f * 1.44269504f) : 1.0f;
  int k0 = ks * 32 + lg * 8, h = n & (HH - 1);
  bf16x8 r;
#pragma unroll
  for (int j = 0; j < 8; ++j) r[j] = f2bf(W[(k0 + j) * HH + h] * sc);
  *(bf16x8*)(WtF + (size_t)idx * 8) = r;
}

// ---------------- xc: x f32 -> xF bf16 frag-order [rt 1024][ks 32][lane 64][8]
// element = x(row = rt*16 + l15, k = ks*32 + lg*8 + j)  (R5-verified layout)
__global__ void xc_kernel(const float* __restrict__ x, short* __restrict__ xF) {
  int idx = blockIdx.x * 256 + threadIdx.x;       // 2,097,152
  int lane = idx & 63, ks = (idx >> 6) & 31, rt = idx >> 11;
  int l15 = lane & 15, lg = lane >> 4;
  const float4* src = (const float4*)(x + (size_t)(rt * 16 + l15) * CC + ks * 32 + lg * 8);
  float4 a = src[0], b = src[1];
  uint4 w;
  w.x = pk2bf(a.x, a.y);  w.y = pk2bf(a.z, a.w);
  w.z = pk2bf(b.x, b.y);  w.w = pk2bf(b.z, b.w);
  *(uint4*)(xF + (size_t)idx * 8) = w;
}

// ---------------- projG: async-staged proj + dbuf MFMA + frag epilogue -------
// grid 1024 (16-row tiles), 256 thr (4 waves), 32 KB LDS -> 4 blocks/CU.
// Stage: 8 global_load_lds issues/wave (wave-uniform LDS base + implicit
// lane*16B; per-lane global addr). LDS = xF tile linear: chunk (ks*64+lane)
// at byte (ks*64+lane)*16 -> A-frag read is contiguous ks*1024 + lane*16.
__launch_bounds__(256, 4)
__global__ void projG_kernel(const short* __restrict__ xF, const short* __restrict__ WtF,
                             short* __restrict__ qo, short* __restrict__ kFo,
                             short* __restrict__ vFo) {
  __shared__ __align__(16) short xs[16384];       // 32 KB staged tile (+ epilogue reuse)
  int t = threadIdx.x;
  int row0 = blockIdx.x * 16;
  int wave = t >> 6, lane = t & 63;
  int l15 = lane & 15, lg = lane >> 4;

  // ---- async stage: wave w covers chunks w*512 .. w*512+511 (8 issues) ----
  {
    const short* gsrc = xF + (size_t)blockIdx.x * 16384 + ((size_t)wave * 512 + lane) * 8;
    short* ldst = xs + (size_t)wave * 4096;   // wave-uniform base (shorts)
#pragma unroll
    for (int k2 = 0; k2 < 8; ++k2)
      gload16(gsrc + k2 * 512, ldst + k2 * 512);
  }

  int nf0 = wave * 3;
  const short* wp = WtF + ((size_t)nf0 * 32 * 64 + (size_t)lane) * 8;

  f32x4 acc[3];
#pragma unroll
  for (int j = 0; j < 3; ++j) acc[j] = (f32x4){0.f, 0.f, 0.f, 0.f};

  WAITVM0();            // own DMA issues landed
  __syncthreads();      // all waves' quarters landed

  bf16x8 wA[3], wB[3];
#pragma unroll
  for (int j = 0; j < 3; ++j) wA[j] = *(const bf16x8*)(wp + (size_t)j * 32 * 512);

#pragma unroll
  for (int ks = 0; ks < 32; ks += 2) {
#pragma unroll
    for (int j = 0; j < 3; ++j)
      wB[j] = *(const bf16x8*)(wp + ((size_t)j * 32 + ks + 1) * 512);
    bf16x8 a0 = *(const bf16x8*)(xs + ks * 512 + lane * 8);
#pragma unroll
    for (int j = 0; j < 3; ++j)
      acc[j] = __builtin_amdgcn_mfma_f32_16x16x32_bf16(a0, wA[j], acc[j], 0, 0, 0);
    if (ks + 2 < 32) {
#pragma unroll
      for (int j = 0; j < 3; ++j)
        wA[j] = *(const bf16x8*)(wp + ((size_t)j * 32 + ks + 2) * 512);
    }
    bf16x8 a1 = *(const bf16x8*)(xs + (ks + 1) * 512 + lane * 8);
#pragma unroll
    for (int j = 0; j < 3; ++j)
      acc[j] = __builtin_amdgcn_mfma_f32_16x16x32_bf16(a1, wB[j], acc[j], 0, 0, 0);
  }

  // ---- epilogue (v17-verified): q row-major; k/v via LDS -> kF/vF ----
  int b  = row0 >> 12;
  int kt = (row0 & 4095) >> 6;
  int cf = (row0 >> 4) & 3;
  short* ksl = xs;           // k stage: [16 rows][72]  (144B rows)
  short* vsl = xs + 1152;    // v stage: [64 h][24]

  __syncthreads();           // staged tile dead; reuse

#pragma unroll
  for (int j = 0; j < 3; ++j) {
    int nf = nf0 + j;
    int h = (nf & 3) * 16 + l15;
    if (nf < 4) {            // q: row-major global
#pragma unroll
      for (int reg = 0; reg < 4; ++reg)
        qo[(size_t)(row0 + lg * 4 + reg) * HH + h] = f2bf(acc[j][reg]);
    } else if (nf < 8) {     // k: stage [row][h], stride 72
#pragma unroll
      for (int reg = 0; reg < 4; ++reg)
        ksl[(lg * 4 + reg) * 72 + h] = f2bf(acc[j][reg]);
    } else {                 // v: stage transposed [h][row], packed
      uint2 w2;
      w2.x = pk2bf(acc[j][0], acc[j][1]);
      w2.y = pk2bf(acc[j][2], acc[j][3]);
      *(uint2*)(vsl + h * 24 + lg * 4) = w2;
    }
  }
  __syncthreads();

  size_t tileoff = ((size_t)b * 64 + kt) * 4096;
  if (t < 128) {             // kF chunks ld = cf*2 + ks2 (full)
    int ks2 = t >> 6, ln = t & 63;
    int l15o = ln & 15, lgo = ln >> 4;
    bf16x8 r = *(const bf16x8*)(ksl + l15o * 72 + ks2 * 32 + lgo * 8);
    *(bf16x8*)(kFo + tileoff + (size_t)(cf * 2 + ks2) * 512 + ln * 8) = r;
  } else if (t < 256) {      // vF chunks ld = hf*2 + (cf>>1), lanes lg-subset
    int t2 = t - 128;
    int hf = t2 >> 5, lgl = (t2 >> 4) & 1, l15o = t2 & 15;
    bf16x8 r = *(const bf16x8*)(vsl + (hf * 16 + l15o) * 24 + lgl * 8);
    int lnout = (2 * (cf & 1) + lgl) * 16 + l15o;
    *(bf16x8*)(vFo + tileoff + (size_t)(hf * 2 + (cf >> 1)) * 512 + lnout * 8) = r;
  }
}

// ---------------- attnW: swapped QK^T + packed P writes ----------------------
// (byte-identical to v15/v16/v17)
__launch_bounds__(512, 4)
__global__ void attnW_kernel(const short* __restrict__ q, const short* __restrict__ kF,
                             const short* __restrict__ vF, float* __restrict__ out) {
  __shared__ __align__(16) short ps[8][2560];
  __shared__ __align__(16) float macc[32][68];
  __shared__ float lL[32];
  int wave = threadIdx.x >> 6, lane = threadIdx.x & 63;
  int l15 = lane & 15, lg = lane >> 4;
  int low3 = blockIdx.x & 7;                 // XCD id (perf heuristic only)
  int b  = low3 >> 1;                        // 2 XCDs per batch -> L2-resident KV
  int qt = ((blockIdx.x >> 3) << 1) | (low3 & 1);   // 0..127
  int brow0 = qt * 32;

  const short* qb = q + ((size_t)b * TT + brow0 + l15) * HH;
  bf16x8 qa[2][2];
#pragma unroll
  for (int g = 0; g < 2; ++g) {
    qa[g][0] = *(const bf16x8*)(qb + g * 16 * HH + lg * 8);
    qa[g][1] = *(const bf16x8*)(qb + g * 16 * HH + 32 + lg * 8);
  }

  bf16x8 ones;
#pragma unroll
  for (int j = 0; j < 8; ++j) ones[j] = (short)0x3F80;   // bf16 1.0

  const short* kfb = kF + (size_t)b * 262144 + (size_t)lane * 8;
  const short* vfb = vF + (size_t)b * 262144 + (size_t)lane * 8;

  f32x4 acc[2][4], accl[2];
#pragma unroll
  for (int g = 0; g < 2; ++g) {
#pragma unroll
    for (int i = 0; i < 4; ++i) acc[g][i] = (f32x4){0.f, 0.f, 0.f, 0.f};
    accl[g] = (f32x4){0.f, 0.f, 0.f, 0.f};
  }

  char* psw = (char*)&ps[wave][0];
  int xorv = (l15 >> 3) << 4;
  int pwbase = l15 * 80;                       // write row = l15 (qrow)
  int pr = l15 * 80 + ((lg << 4) ^ xorv);      // read: row=l15, colbytes lg*16..

  for (int t = wave * 16; t < wave * 16 + 16; ++t) {
    const short* kp = kfb + (size_t)t * 2048;
    const short* vp = vfb + (size_t)(t >> 1) * 4096 + (size_t)(t & 1) * 512;
    bf16x8 kf[4], vf[4];
#pragma unroll
    for (int ld = 0; ld < 4; ++ld) kf[ld] = *(const bf16x8*)(kp + ld * 512);
#pragma unroll
    for (int hf = 0; hf < 4; ++hf) vf[hf] = *(const bf16x8*)(vp + hf * 1024);
#pragma unroll
    for (int g = 0; g < 2; ++g)
#pragma unroll
      for (int cf = 0; cf < 2; ++cf) {
        f32x4 t4 = (f32x4){0.f, 0.f, 0.f, 0.f};
        t4 = __builtin_amdgcn_mfma_f32_16x16x32_bf16(kf[cf * 2], qa[g][0], t4, 0, 0, 0);
        t4 = __builtin_amdgcn_mfma_f32_16x16x32_bf16(kf[cf * 2 + 1], qa[g][1], t4, 0, 0, 0);
        float p0 = EXP2(t4[0]), p1 = EXP2(t4[1]);
        float p2 = EXP2(t4[2]), p3 = EXP2(t4[3]);
        unsigned w01 = pk2bf(p0, p1);
        unsigned w23 = pk2bf(p2, p3);
        int cb = (cf << 5) + (lg << 3);        // column byte = kv*2
        *(unsigned*)(psw + g * 1280 + pwbase + ((cb) ^ xorv)) = w01;
        *(unsigned*)(psw + g * 1280 + pwbase + ((cb + 4) ^ xorv)) = w23;
      }
    bf16x8 pa0 = *(const bf16x8*)(psw + pr);
    bf16x8 pa1 = *(const bf16x8*)(psw + 1280 + pr);
    __builtin_amdgcn_s_setprio(1);
#pragma unroll
    for (int hf = 0; hf < 4; ++hf) {
      acc[0][hf] = __builtin_amdgcn_mfma_f32_16x16x32_bf16(pa0, vf[hf], acc[0][hf], 0, 0, 0);
      acc[1][hf] = __builtin_amdgcn_mfma_f32_16x16x32_bf16(pa1, vf[hf], acc[1][hf], 0, 0, 0);
    }
    accl[0] = __builtin_amdgcn_mfma_f32_16x16x32_bf16(pa0, ones, accl[0], 0, 0, 0);
    accl[1] = __builtin_amdgcn_mfma_f32_16x16x32_bf16(pa1, ones, accl[1], 0, 0, 0);
    __builtin_amdgcn_s_setprio(0);
  }

#pragma unroll
  for (int ph = 0; ph < 8; ++ph) {
    if (wave == ph) {
#pragma unroll
      for (int g = 0; g < 2; ++g)
#pragma unroll
        for (int reg = 0; reg < 4; ++reg) {
          int row = g * 16 + lg * 4 + reg;
          if (ph == 0) {
#pragma unroll
            for (int hf = 0; hf < 4; ++hf)
              macc[row][hf * 16 + l15] = acc[g][hf][reg];
            if (l15 == 0) lL[row] = accl[g][reg];
          } else {
#pragma unroll
            for (int hf = 0; hf < 4; ++hf)
              macc[row][hf * 16 + l15] += acc[g][hf][reg];
            if (l15 == 0) lL[row] += accl[g][reg];
          }
        }
    }
    __syncthreads();
  }

  {
    int tt = threadIdx.x;
    int r = tt >> 4, c0 = (tt & 15) * 4;
    float linv = 1.0f / lL[r];
    float4 o;
    o.x = macc[r][c0 + 0] * linv; o.y = macc[r][c0 + 1] * linv;
    o.z = macc[r][c0 + 2] * linv; o.w = macc[r][c0 + 3] * linv;
    *(float4*)(out + ((size_t)b * TT + brow0 + r) * HH + c0) = o;
  }
}

extern "C" void kernel_launch(void* const* d_in, const int* in_sizes, int n_in,
                              void* d_out, int out_size, void* d_ws, size_t ws_size,
                              hipStream_t stream) {
  const float* x  = (const float*)d_in[0];
  const float* Wq = (const float*)d_in[1];
  const float* Wk = (const float*)d_in[2];
  const float* Wv = (const float*)d_in[3];
  float* out = (float*)d_out;

  char* ws = (char*)d_ws;
  short* WtF = (short*)ws;                 // 384 KB (pad to 512K)
  short* q   = (short*)(ws + 0x080000);    // 2 MB
  short* kF  = (short*)(ws + 0x280000);    // 2 MB
  short* vF  = (short*)(ws + 0x480000);    // 2 MB
  short* xF  = (short*)(ws + 0x680000);    // 32 MB -> 0x2680000 (38.5 MB)

  hipLaunchKernelGGL(wtf_kernel,   dim3(96),   dim3(256), 0, stream, Wq, Wk, Wv, WtF);
  hipLaunchKernelGGL(xc_kernel,    dim3(8192), dim3(256), 0, stream, x, xF);
  hipLaunchKernelGGL(projG_kernel, dim3(1024), dim3(256), 0, stream, xF, WtF, q, kF, vF);
  hipLaunchKernelGGL(attnW_kernel, dim3(512),  dim3(512), 0, stream, q, kF, vF, out);
}

// Round 23
// 65.165 us; speedup vs baseline: 1.1328x; 1.1328x over previous
//
#include <hip/hip_runtime.h>
#include <hip/hip_bf16.h>

// Head attention: x[4,4096,1024] f32, Wq/Wk/Wv[1024,64] f32 -> out[4,4096,64] f32
// v23: projX = global_load_lds staging DIRECTLY from f32 x (per-lane global
//   source addrs carry the frag permutation + XOR bank-swizzle; LDS dest
//   linear -- rule #21/m173). Deletes v22's xc pre-pass (96 MB round-trip).
//   f32->bf16 cvt on the read side (cvt_pk, overlaps MFMA). Swizzle:
//   unit v stores logical u = v ^ ((v>>3)&7) (involution); read applies same.
//   wtf/attnW byte-identical to v17/v19.

#define BB 4
#define TT 4096
#define CC 1024
#define HH 64

typedef __attribute__((ext_vector_type(8))) short bf16x8;
typedef __attribute__((ext_vector_type(4))) float f32x4;

#if __has_builtin(__builtin_amdgcn_exp2f)
#define EXP2(x) __builtin_amdgcn_exp2f(x)
#else
#define EXP2(x) exp2f(x)
#endif

__device__ __forceinline__ short f2bf(float f) {
  union { float f; unsigned u; } v; v.f = f;
  unsigned r = v.u + 0x7fffu + ((v.u >> 16) & 1u);  // RNE
  return (short)(r >> 16);
}

__device__ __forceinline__ unsigned pk2bf(float lo, float hi) {  // packed RNE cvt
  __hip_bfloat162 p = __float22bfloat162_rn(make_float2(lo, hi));
  return *reinterpret_cast<unsigned*>(&p);
}

__device__ __forceinline__ void gload16(const void* g, short* l) {
  __builtin_amdgcn_global_load_lds(
      (const __attribute__((address_space(1))) void*)g,
      (__attribute__((address_space(3))) void*)l, 16, 0, 0);
}

#define WAITVM0() asm volatile("s_waitcnt vmcnt(0)" ::: "memory")

// ---------------- wtf: W -> WtF[nf 12][ks 32][lane 64][8] bf16 ---------------
// q part scaled by C^-0.5 * log2(e)  (softmax exp == exp2 of logits)
__global__ void wtf_kernel(const float* __restrict__ Wq, const float* __restrict__ Wk,
                           const float* __restrict__ Wv, short* __restrict__ WtF) {
  int idx = blockIdx.x * 256 + threadIdx.x;       // 24576
  int lane = idx & 63, ks = (idx >> 6) & 31, nf = idx >> 11;
  int l15 = lane & 15, lg = lane >> 4;
  int n = nf * 16 + l15;
  const float* W = (n < HH) ? Wq : ((n < 2 * HH) ? Wk : Wv);
  float sc = (n < HH) ? (0.03125f * 1.44269504f) : 1.0f;
  int k0 = ks * 32 + lg * 8, h = n & (HH - 1);
  bf16x8 r;
#pragma unroll
  for (int j = 0; j < 8; ++j) r[j] = f2bf(W[(k0 + j) * HH + h] * sc);
  *(bf16x8*)(WtF + (size_t)idx * 8) = r;
}

// ---------------- projX: f32-direct DMA staging + dbuf MFMA + epilogue -------
// grid 1024 (16-row tiles), 256 thr (4 waves), 64 KB LDS -> 2 blocks/CU.
// DMA: 16 issues/wave; 16B-unit v = wave*1024 + k2*64 + lane holds logical
// unit u = v ^ (lane>>3), where u = ks*128 + ln*2 + h <-> floats
// x(row0 + (ln&15), ks*32 + (ln>>4)*8 + h*4 ..+3). Read: lane's A-frag
// units u0 = ks*128 + lane*2 (+1) at swizzled addr u ^ ((lane>>2)&7) --
// uniform 8 lanes/bank-cluster (conflict-free b128). cvt_pk to bf16 inline.
__launch_bounds__(256, 2)
__global__ void projX_kernel(const float* __restrict__ x, const short* __restrict__ WtF,
                             short* __restrict__ qo, short* __restrict__ kFo,
                             short* __restrict__ vFo) {
  __shared__ __align__(16) short xs[32768];   // 64 KB swizzled f32 tile (+ epilogue reuse)
  int t = threadIdx.x;
  int row0 = blockIdx.x * 16;
  int wave = t >> 6, lane = t & 63;
  int l15 = lane & 15, lg = lane >> 4;

  // ---- async DMA stage ----
  {
    const float* xb = x + (size_t)row0 * CC;
    int lp = lane ^ (lane >> 3);            // logical-unit low bits for this lane
#pragma unroll
    for (int k2 = 0; k2 < 16; ++k2) {
      int ks = wave * 8 + (k2 >> 1);
      int ln = (k2 & 1) * 32 + (lp >> 1);
      int h  = lp & 1;
      const float* src = xb + (size_t)(ln & 15) * CC + ks * 32 + (ln >> 4) * 8 + h * 4;
      short* dst = xs + ((size_t)wave * 1024 + (size_t)k2 * 64) * 8;  // unit*8 shorts
      gload16(src, dst);
    }
  }

  int nf0 = wave * 3;
  const short* wp = WtF + ((size_t)nf0 * 32 * 64 + (size_t)lane) * 8;

  f32x4 acc[3];
#pragma unroll
  for (int j = 0; j < 3; ++j) acc[j] = (f32x4){0.f, 0.f, 0.f, 0.f};

  WAITVM0();            // own DMA issues landed
  __syncthreads();      // all waves' sections landed

  const char* xsb = (const char*)xs;
  int m = (lane >> 2) & 7;
  int roA = ((lane * 2) ^ m) * 16;        // byte offset within ks-slab (2048 B)
  int roB = ((lane * 2 + 1) ^ m) * 16;

#define LDA(KS, AV)                                                  \
  {                                                                  \
    float4 fa_ = *(const float4*)(xsb + (KS) * 2048 + roA);          \
    float4 fb_ = *(const float4*)(xsb + (KS) * 2048 + roB);          \
    unsigned* au_ = (unsigned*)&(AV);                                \
    au_[0] = pk2bf(fa_.x, fa_.y); au_[1] = pk2bf(fa_.z, fa_.w);      \
    au_[2] = pk2bf(fb_.x, fb_.y); au_[3] = pk2bf(fb_.z, fb_.w);      \
  }

  bf16x8 wA[3], wB[3];
#pragma unroll
  for (int j = 0; j < 3; ++j) wA[j] = *(const bf16x8*)(wp + (size_t)j * 32 * 512);

#pragma unroll
  for (int ks = 0; ks < 32; ks += 2) {
#pragma unroll
    for (int j = 0; j < 3; ++j)
      wB[j] = *(const bf16x8*)(wp + ((size_t)j * 32 + ks + 1) * 512);
    bf16x8 a0;
    LDA(ks, a0)
#pragma unroll
    for (int j = 0; j < 3; ++j)
      acc[j] = __builtin_amdgcn_mfma_f32_16x16x32_bf16(a0, wA[j], acc[j], 0, 0, 0);
    if (ks + 2 < 32) {
#pragma unroll
      for (int j = 0; j < 3; ++j)
        wA[j] = *(const bf16x8*)(wp + ((size_t)j * 32 + ks + 2) * 512);
    }
    bf16x8 a1;
    LDA(ks + 1, a1)
#pragma unroll
    for (int j = 0; j < 3; ++j)
      acc[j] = __builtin_amdgcn_mfma_f32_16x16x32_bf16(a1, wB[j], acc[j], 0, 0, 0);
  }
#undef LDA

  // ---- epilogue (v17-verified): q row-major; k/v via LDS -> kF/vF ----
  int b  = row0 >> 12;
  int kt = (row0 & 4095) >> 6;
  int cf = (row0 >> 4) & 3;
  short* ksl = xs;           // k stage: [16 rows][72]  (144B rows)
  short* vsl = xs + 1152;    // v stage: [64 h][24]

  __syncthreads();           // staged tile dead; reuse

#pragma unroll
  for (int j = 0; j < 3; ++j) {
    int nf = nf0 + j;
    int h = (nf & 3) * 16 + l15;
    if (nf < 4) {            // q: row-major global
#pragma unroll
      for (int reg = 0; reg < 4; ++reg)
        qo[(size_t)(row0 + lg * 4 + reg) * HH + h] = f2bf(acc[j][reg]);
    } else if (nf < 8) {     // k: stage [row][h], stride 72
#pragma unroll
      for (int reg = 0; reg < 4; ++reg)
        ksl[(lg * 4 + reg) * 72 + h] = f2bf(acc[j][reg]);
    } else {                 // v: stage transposed [h][row], packed
      uint2 w2;
      w2.x = pk2bf(acc[j][0], acc[j][1]);
      w2.y = pk2bf(acc[j][2], acc[j][3]);
      *(uint2*)(vsl + h * 24 + lg * 4) = w2;
    }
  }
  __syncthreads();

  size_t tileoff = ((size_t)b * 64 + kt) * 4096;
  if (t < 128) {             // kF chunks ld = cf*2 + ks2 (full)
    int ks2 = t >> 6, ln = t & 63;
    int l15o = ln & 15, lgo = ln >> 4;
    bf16x8 r = *(const bf16x8*)(ksl + l15o * 72 + ks2 * 32 + lgo * 8);
    *(bf16x8*)(kFo + tileoff + (size_t)(cf * 2 + ks2) * 512 + ln * 8) = r;
  } else if (t < 256) {      // vF chunks ld = hf*2 + (cf>>1), lanes lg-subset
    int t2 = t - 128;
    int hf = t2 >> 5, lgl = (t2 >> 4) & 1, l15o = t2 & 15;
    bf16x8 r = *(const bf16x8*)(vsl + (hf * 16 + l15o) * 24 + lgl * 8);
    int lnout = (2 * (cf & 1) + lgl) * 16 + l15o;
    *(bf16x8*)(vFo + tileoff + (size_t)(hf * 2 + (cf >> 1)) * 512 + lnout * 8) = r;
  }
}

// ---------------- attnW: swapped QK^T + packed P writes ----------------------
// (byte-identical to v15/v16/v17/v19)
__launch_bounds__(512, 4)
__global__ void attnW_kernel(const short* __restrict__ q, const short* __restrict__ kF,
                             const short* __restrict__ vF, float* __restrict__ out) {
  __shared__ __align__(16) short ps[8][2560];
  __shared__ __align__(16) float macc[32][68];
  __shared__ float lL[32];
  int wave = threadIdx.x >> 6, lane = threadIdx.x & 63;
  int l15 = lane & 15, lg = lane >> 4;
  int low3 = blockIdx.x & 7;                 // XCD id (perf heuristic only)
  int b  = low3 >> 1;                        // 2 XCDs per batch -> L2-resident KV
  int qt = ((blockIdx.x >> 3) << 1) | (low3 & 1);   // 0..127
  int brow0 = qt * 32;

  const short* qb = q + ((size_t)b * TT + brow0 + l15) * HH;
  bf16x8 qa[2][2];
#pragma unroll
  for (int g = 0; g < 2; ++g) {
    qa[g][0] = *(const bf16x8*)(qb + g * 16 * HH + lg * 8);
    qa[g][1] = *(const bf16x8*)(qb + g * 16 * HH + 32 + lg * 8);
  }

  bf16x8 ones;
#pragma unroll
  for (int j = 0; j < 8; ++j) ones[j] = (short)0x3F80;   // bf16 1.0

  const short* kfb = kF + (size_t)b * 262144 + (size_t)lane * 8;
  const short* vfb = vF + (size_t)b * 262144 + (size_t)lane * 8;

  f32x4 acc[2][4], accl[2];
#pragma unroll
  for (int g = 0; g < 2; ++g) {
#pragma unroll
    for (int i = 0; i < 4; ++i) acc[g][i] = (f32x4){0.f, 0.f, 0.f, 0.f};
    accl[g] = (f32x4){0.f, 0.f, 0.f, 0.f};
  }

  char* psw = (char*)&ps[wave][0];
  int xorv = (l15 >> 3) << 4;
  int pwbase = l15 * 80;                       // write row = l15 (qrow)
  int pr = l15 * 80 + ((lg << 4) ^ xorv);      // read: row=l15, colbytes lg*16..

  for (int t = wave * 16; t < wave * 16 + 16; ++t) {
    const short* kp = kfb + (size_t)t * 2048;
    const short* vp = vfb + (size_t)(t >> 1) * 4096 + (size_t)(t & 1) * 512;
    bf16x8 kf[4], vf[4];
#pragma unroll
    for (int ld = 0; ld < 4; ++ld) kf[ld] = *(const bf16x8*)(kp + ld * 512);
#pragma unroll
    for (int hf = 0; hf < 4; ++hf) vf[hf] = *(const bf16x8*)(vp + hf * 1024);
#pragma unroll
    for (int g = 0; g < 2; ++g)
#pragma unroll
      for (int cf = 0; cf < 2; ++cf) {
        f32x4 t4 = (f32x4){0.f, 0.f, 0.f, 0.f};
        t4 = __builtin_amdgcn_mfma_f32_16x16x32_bf16(kf[cf * 2], qa[g][0], t4, 0, 0, 0);
        t4 = __builtin_amdgcn_mfma_f32_16x16x32_bf16(kf[cf * 2 + 1], qa[g][1], t4, 0, 0, 0);
        float p0 = EXP2(t4[0]), p1 = EXP2(t4[1]);
        float p2 = EXP2(t4[2]), p3 = EXP2(t4[3]);
        unsigned w01 = pk2bf(p0, p1);
        unsigned w23 = pk2bf(p2, p3);
        int cb = (cf << 5) + (lg << 3);        // column byte = kv*2
        *(unsigned*)(psw + g * 1280 + pwbase + ((cb) ^ xorv)) = w01;
        *(unsigned*)(psw + g * 1280 + pwbase + ((cb + 4) ^ xorv)) = w23;
      }
    bf16x8 pa0 = *(const bf16x8*)(psw + pr);
    bf16x8 pa1 = *(const bf16x8*)(psw + 1280 + pr);
    __builtin_amdgcn_s_setprio(1);
#pragma unroll
    for (int hf = 0; hf < 4; ++hf) {
      acc[0][hf] = __builtin_amdgcn_mfma_f32_16x16x32_bf16(pa0, vf[hf], acc[0][hf], 0, 0, 0);
      acc[1][hf] = __builtin_amdgcn_mfma_f32_16x16x32_bf16(pa1, vf[hf], acc[1][hf], 0, 0, 0);
    }
    accl[0] = __builtin_amdgcn_mfma_f32_16x16x32_bf16(pa0, ones, accl[0], 0, 0, 0);
    accl[1] = __builtin_amdgcn_mfma_f32_16x16x32_bf16(pa1, ones, accl[1], 0, 0, 0);
    __builtin_amdgcn_s_setprio(0);
  }

#pragma unroll
  for (int ph = 0; ph < 8; ++ph) {
    if (wave == ph) {
#pragma unroll
      for (int g = 0; g < 2; ++g)
#pragma unroll
        for (int reg = 0; reg < 4; ++reg) {
          int row = g * 16 + lg * 4 + reg;
          if (ph == 0) {
#pragma unroll
            for (int hf = 0; hf < 4; ++hf)
              macc[row][hf * 16 + l15] = acc[g][hf][reg];
            if (l15 == 0) lL[row] = accl[g][reg];
          } else {
#pragma unroll
            for (int hf = 0; hf < 4; ++hf)
              macc[row][hf * 16 + l15] += acc[g][hf][reg];
            if (l15 == 0) lL[row] += accl[g][reg];
          }
        }
    }
    __syncthreads();
  }

  {
    int tt = threadIdx.x;
    int r = tt >> 4, c0 = (tt & 15) * 4;
    float linv = 1.0f / lL[r];
    float4 o;
    o.x = macc[r][c0 + 0] * linv; o.y = macc[r][c0 + 1] * linv;
    o.z = macc[r][c0 + 2] * linv; o.w = macc[r][c0 + 3] * linv;
    *(float4*)(out + ((size_t)b * TT + brow0 + r) * HH + c0) = o;
  }
}

extern "C" void kernel_launch(void* const* d_in, const int* in_sizes, int n_in,
                              void* d_out, int out_size, void* d_ws, size_t ws_size,
                              hipStream_t stream) {
  const float* x  = (const float*)d_in[0];
  const float* Wq = (const float*)d_in[1];
  const float* Wk = (const float*)d_in[2];
  const float* Wv = (const float*)d_in[3];
  float* out = (float*)d_out;

  char* ws = (char*)d_ws;
  short* WtF = (short*)ws;                 // 384 KB (pad to 512K)
  short* q   = (short*)(ws + 0x080000);    // 2 MB
  short* kF  = (short*)(ws + 0x280000);    // 2 MB
  short* vF  = (short*)(ws + 0x480000);    // 2 MB -> 6.5 MB total

  hipLaunchKernelGGL(wtf_kernel,   dim3(96),   dim3(256), 0, stream, Wq, Wk, Wv, WtF);
  hipLaunchKernelGGL(projX_kernel, dim3(1024), dim3(256), 0, stream, x, WtF, q, kF, vF);
  hipLaunchKernelGGL(attnW_kernel, dim3(512),  dim3(512), 0, stream, q, kF, vF, out);
}